// Round 1
// baseline (782.286 us; speedup 1.0000x reference)
//
#include <hip/hip_runtime.h>
#include <hip/hip_bf16.h>

#define NODELEN 17949
#define NN 512
#define NE 4096
#define H2 768
#define EMB 128
#define IN_DIM (2 * NODELEN)      // 35898
#define KP1 35904                 // IN_DIM padded to 64 (561 * 64)
#define KITERS1 561
#define SPLITS 24
#define KCHUNK1 24                // ceil(561/24)

#define BM 128
#define BN 128
#define BK 64
#define LDT (BK + 8)              // LDS row stride in bf16 (pad 16B)

typedef __bf16 bf16x8 __attribute__((ext_vector_type(8)));
typedef float f32x4 __attribute__((ext_vector_type(4)));

// ---------------- graph prep (dense adjacency) ----------------

__global__ void k_zero_int(int* p, int n) {
    int i = blockIdx.x * 256 + threadIdx.x;
    if (i < n) p[i] = 0;
}

__global__ void k_zero_f4(float4* p, int n4) {
    int i = blockIdx.x * 256 + threadIdx.x;
    if (i < n4) p[i] = make_float4(0.f, 0.f, 0.f, 0.f);
}

__global__ void k_deg(const int* __restrict__ dst, int* __restrict__ cnt) {
    int e = blockIdx.x * 256 + threadIdx.x;
    if (e < NE) atomicAdd(&cnt[dst[e]], 1);
}

__global__ void k_invdeg(const int* __restrict__ cnt, float* __restrict__ invdeg) {
    int i = blockIdx.x * 256 + threadIdx.x;
    if (i < NN) {
        int c = cnt[i];
        invdeg[i] = 1.0f / (float)(c > 1 ? c : 1);
    }
}

// A[dst][src] += 1/deg[dst]  (duplicates accumulate identical values -> order-safe)
__global__ void k_scatter(const int* __restrict__ src, const int* __restrict__ dst,
                          const float* __restrict__ invdeg, float* __restrict__ A) {
    int e = blockIdx.x * 256 + threadIdx.x;
    if (e < NE) {
        int d = dst[e];
        atomicAdd(&A[(size_t)d * NN + src[e]], invdeg[d]);
    }
}

// A2b = bf16(A @ A), exploiting row sparsity (uniform branch on broadcast value)
__global__ void k_a2(const float* __restrict__ A, __bf16* __restrict__ A2b) {
    int i = blockIdx.x;
    int t = threadIdx.x;   // 256
    __shared__ float row[NN];
    row[t] = A[(size_t)i * NN + t];
    row[t + 256] = A[(size_t)i * NN + 256 + t];
    __syncthreads();
    float a0 = 0.f, a1 = 0.f;
    for (int s = 0; s < NN; ++s) {
        float a = row[s];
        if (a != 0.f) {
            a0 += a * A[(size_t)s * NN + t];
            a1 += a * A[(size_t)s * NN + 256 + t];
        }
    }
    A2b[(size_t)i * NN + t] = (__bf16)a0;
    A2b[(size_t)i * NN + 256 + t] = (__bf16)a1;
}

// Fused: xT[f][s] = bf16(x[s][f]) (tiled transpose)  AND  embb x-half (col0 zero).
// Reads x exactly once.
__global__ void k_xt_emb(const float* __restrict__ x, __bf16* __restrict__ xT,
                         __bf16* __restrict__ embb) {
    __shared__ float t[64][65];
    int f0 = blockIdx.x * 64, s0 = blockIdx.y * 64;
    int tx = threadIdx.x & 63, ty = threadIdx.x >> 6;   // ty 0..3
#pragma unroll
    for (int r = 0; r < 16; ++r) {
        int f = f0 + tx;
        int s = s0 + ty * 16 + r;
        float v = (f < NODELEN) ? x[(size_t)s * NODELEN + f] : 0.f;
        t[ty * 16 + r][tx] = v;
        if (f < NODELEN)
            embb[(size_t)s * KP1 + f] = (__bf16)((f == 0) ? 0.f : v);
    }
    __syncthreads();
#pragma unroll
    for (int r = 0; r < 16; ++r) {
        int f = f0 + ty * 16 + r;
        if (f < NODELEN) xT[(size_t)f * NN + s0 + tx] = (__bf16)t[tx][ty * 16 + r];
    }
}

// zero pad cols [IN_DIM, KP1) of embb
__global__ void k_pad(__bf16* __restrict__ embb) {
    int i = blockIdx.x * 256 + threadIdx.x;
    const int PAD = KP1 - IN_DIM;   // 6
    if (i < NN * PAD) {
        int n = i / PAD, c = i % PAD;
        embb[(size_t)n * KP1 + IN_DIM + c] = (__bf16)0.f;
    }
}

// ---------------- MFMA GEMM: C[m][n] = sum_k A_bf16[m][k] * B[n][k] ----------------
// EPI: 0 = split-K partials (f32), 1 = f32 out + bias (n<Nvalid), 2 = bf16 out into
//      embb h2-half (col n==0 zeroed). BF16B: B is bf16 (plain copy staging) else f32
//      (converted during staging; Kvalid guards the k-tail).
// XCD-swizzled (logical x fastest -> same-B-panel / same-z blocks share an XCD L2).
// Register double-buffer: next tile's global loads are issued right after the first
// barrier so HBM latency hides under the MFMA phase.

#define GLOAD(K0)                                                                    \
    do {                                                                             \
        const uint4* Ag_ = (const uint4*)(Arow + (K0));                              \
        _Pragma("unroll")                                                            \
        for (int i_ = 0; i_ < 4; ++i_) av[i_] = Ag_[i_];                             \
        if (BF16B) {                                                                 \
            if (nok) {                                                               \
                const uint4* Bg_ = (const uint4*)(Brow_h + (K0));                    \
                _Pragma("unroll")                                                    \
                for (int i_ = 0; i_ < 4; ++i_) bvh[i_] = Bg_[i_];                    \
            } else {                                                                 \
                _Pragma("unroll")                                                    \
                for (int i_ = 0; i_ < 4; ++i_) bvh[i_] = make_uint4(0, 0, 0, 0);     \
            }                                                                        \
        } else {                                                                     \
            if (nok && ((K0) + spart * 32 + 32 <= Kvalid)) {                         \
                const float4* Bg_ = (const float4*)(Brow_f + (K0));                  \
                _Pragma("unroll")                                                    \
                for (int j_ = 0; j_ < 8; ++j_) bvf[j_] = Bg_[j_];                    \
            } else {                                                                 \
                _Pragma("unroll")                                                    \
                for (int j_ = 0; j_ < 8; ++j_) {                                     \
                    int kb_ = (K0) + spart * 32 + j_ * 4;                            \
                    float4 v_;                                                       \
                    v_.x = (nok && kb_ + 0 < Kvalid) ? Brow_f[(K0) + j_ * 4 + 0] : 0.f; \
                    v_.y = (nok && kb_ + 1 < Kvalid) ? Brow_f[(K0) + j_ * 4 + 1] : 0.f; \
                    v_.z = (nok && kb_ + 2 < Kvalid) ? Brow_f[(K0) + j_ * 4 + 2] : 0.f; \
                    v_.w = (nok && kb_ + 3 < Kvalid) ? Brow_f[(K0) + j_ * 4 + 3] : 0.f; \
                    bvf[j_] = v_;                                                    \
                }                                                                    \
            }                                                                        \
        }                                                                            \
    } while (0)

template <int EPI, bool BF16B>
__global__ __launch_bounds__(256) void gemm_k(
        const __bf16* __restrict__ A, int lda,
        const void* __restrict__ Bv, int ldb,
        int Nvalid, int Kvalid, int kIters, int kChunk,
        float* __restrict__ Cf, int ldc, const float* __restrict__ bias,
        __bf16* __restrict__ Cb) {
    __shared__ __align__(16) __bf16 As[BM][LDT];
    __shared__ __align__(16) __bf16 Bs[BN][LDT];

    const int tid = threadIdx.x;

    // ---- XCD-aware bijective swizzle (dispatch fid -> XCD = fid % 8) ----
    const int gx = gridDim.x, gy = gridDim.y;
    const int nwg = gx * gy * (int)gridDim.z;
    const int fid = blockIdx.x + gx * (blockIdx.y + gy * blockIdx.z);
    const int q = nwg >> 3, r = nwg & 7;
    const int xcd = fid & 7, idx = fid >> 3;
    const int lid = (xcd < r) ? xcd * (q + 1) + idx
                              : r * (q + 1) + (xcd - r) * q + idx;
    const int m0 = (lid % gx) * BM;
    const int rem = lid / gx;
    const int n0 = (rem % gy) * BN;
    const int z = rem / gy;

    int it0 = z * kChunk;
    int it1 = it0 + kChunk;
    if (it1 > kIters) it1 = kIters;

    const int wave = tid >> 6;
    const int lane = tid & 63;
    const int wm = (wave & 1) * 64;
    const int wn = (wave >> 1) * 64;
    const int fl = lane & 15;
    const int fq = lane >> 4;

    const int srow = tid >> 1;       // 0..127
    const int spart = tid & 1;       // k offset 0/32

    f32x4 acc[4][4] = {};

    const int bn = n0 + srow;
    const bool nok = bn < Nvalid;
    const __bf16* Arow = A + (size_t)(m0 + srow) * lda + spart * 32;
    const __bf16* Brow_h = (const __bf16*)Bv + (size_t)bn * ldb + spart * 32;
    const float* Brow_f = (const float*)Bv + (size_t)bn * ldb + spart * 32;

    uint4 av[4];
    uint4 bvh[4];
    float4 bvf[8];

    if (it0 < it1) GLOAD(it0 * BK);

    for (int it = it0; it < it1; ++it) {
        // regs -> LDS (compiler inserts vmcnt wait for arrived loads)
#pragma unroll
        for (int i = 0; i < 4; ++i)
            *(uint4*)&As[srow][spart * 32 + i * 8] = av[i];
        if (BF16B) {
#pragma unroll
            for (int i = 0; i < 4; ++i)
                *(uint4*)&Bs[srow][spart * 32 + i * 8] = bvh[i];
        } else {
            __align__(16) __bf16 bl[32];
#pragma unroll
            for (int j = 0; j < 8; ++j) {
                bl[4 * j + 0] = (__bf16)bvf[j].x;
                bl[4 * j + 1] = (__bf16)bvf[j].y;
                bl[4 * j + 2] = (__bf16)bvf[j].z;
                bl[4 * j + 3] = (__bf16)bvf[j].w;
            }
#pragma unroll
            for (int qq = 0; qq < 4; ++qq)
                *(uint4*)&Bs[srow][spart * 32 + qq * 8] = *(uint4*)&bl[qq * 8];
        }
        __syncthreads();

        // issue next tile's loads: they fly under the MFMA phase below
        if (it + 1 < it1) GLOAD((it + 1) * BK);

#pragma unroll
        for (int ks = 0; ks < 2; ++ks) {
            int kk = ks * 32 + fq * 8;
            bf16x8 af[4], bf[4];
#pragma unroll
            for (int i = 0; i < 4; ++i)
                af[i] = *(const bf16x8*)&As[wm + i * 16 + fl][kk];
#pragma unroll
            for (int j = 0; j < 4; ++j)
                bf[j] = *(const bf16x8*)&Bs[wn + j * 16 + fl][kk];
#pragma unroll
            for (int i = 0; i < 4; ++i)
#pragma unroll
                for (int j = 0; j < 4; ++j)
                    acc[i][j] = __builtin_amdgcn_mfma_f32_16x16x32_bf16(
                        af[i], bf[j], acc[i][j], 0, 0, 0);
        }
        __syncthreads();
    }

    // epilogue
#pragma unroll
    for (int i = 0; i < 4; ++i) {
#pragma unroll
        for (int j = 0; j < 4; ++j) {
#pragma unroll
            for (int rr = 0; rr < 4; ++rr) {
                int m = m0 + wm + i * 16 + fq * 4 + rr;
                int n = n0 + wn + j * 16 + fl;
                float v = acc[i][j][rr];
                if (EPI == 0) {
                    Cf[((size_t)z * NN + m) * H2 + n] = v;
                } else if (EPI == 1) {
                    if (n < Nvalid) Cf[(size_t)m * ldc + n] = v + bias[n];
                } else {
                    if (n < Nvalid)
                        Cb[(size_t)m * KP1 + NODELEN + n] = (n == 0) ? (__bf16)0.f : (__bf16)v;
                }
            }
        }
    }
}

// h = relu(sum_z partials + b_e2)
__global__ void k_reduce(const float* __restrict__ partials,
                         const float* __restrict__ bias, float* __restrict__ h) {
    int idx = blockIdx.x * 256 + threadIdx.x;
    if (idx >= NN * H2) return;
    float s = 0.f;
#pragma unroll
    for (int zz = 0; zz < SPLITS; ++zz) s += partials[(size_t)zz * NN * H2 + idx];
    s += bias[idx % H2];
    h[idx] = s > 0.f ? s : 0.f;
}

// encoded[m][e] = h[m] . W_e3[e] + b_e3[e]
__global__ void k_enc(const float* __restrict__ h, const float* __restrict__ W,
                      const float* __restrict__ b, float* __restrict__ out) {
    int m = blockIdx.x, e = threadIdx.x;
    const float4* hr = (const float4*)(h + (size_t)m * H2);
    const float4* wr = (const float4*)(W + (size_t)e * H2);
    float s = 0.f;
#pragma unroll 4
    for (int i = 0; i < H2 / 4; ++i) {
        float4 a = hr[i];
        float4 w = wr[i];
        s += a.x * w.x + a.y * w.y + a.z * w.z + a.w * w.w;
    }
    out[(size_t)m * EMB + e] = s + b[e];
}

// hd_b[m][j] = bf16(relu(enc[m] . W_d1[j] + b_d1[j]))
__global__ void k_dec1(const float* __restrict__ enc, const float* __restrict__ W,
                       const float* __restrict__ b, __bf16* __restrict__ hd) {
    int m = blockIdx.x;
    __shared__ float er[EMB];
    if (threadIdx.x < EMB) er[threadIdx.x] = enc[(size_t)m * EMB + threadIdx.x];
    __syncthreads();
    for (int j = threadIdx.x; j < H2; j += 256) {
        const float4* wr = (const float4*)(W + (size_t)j * EMB);
        float s = 0.f;
#pragma unroll
        for (int i = 0; i < EMB / 4; ++i) {
            float4 w = wr[i];
            s += w.x * er[4 * i] + w.y * er[4 * i + 1] + w.z * er[4 * i + 2] +
                 w.w * er[4 * i + 3];
        }
        float v = s + b[j];
        hd[(size_t)m * H2 + j] = (__bf16)(v > 0.f ? v : 0.f);
    }
}

// ---------------- launch ----------------

extern "C" void kernel_launch(void* const* d_in, const int* in_sizes, int n_in,
                              void* d_out, int out_size, void* d_ws, size_t ws_size,
                              hipStream_t stream) {
    const float* x = (const float*)d_in[0];
    const int* esrc = (const int*)d_in[1];
    const int* edst = (const int*)d_in[2];
    const float* W_e2 = (const float*)d_in[3];
    const float* b_e2 = (const float*)d_in[4];
    const float* W_e3 = (const float*)d_in[5];
    const float* b_e3 = (const float*)d_in[6];
    const float* W_d1 = (const float*)d_in[7];
    const float* b_d1 = (const float*)d_in[8];
    const float* W_d3 = (const float*)d_in[9];
    const float* b_d3 = (const float*)d_in[10];
    float* out = (float*)d_out;

    char* w = (char*)d_ws;
    auto alloc = [&](size_t bytes) {
        char* p = w;
        w += (bytes + 255) & ~(size_t)255;
        return p;
    };
    __bf16* embb = (__bf16*)alloc((size_t)NN * KP1 * 2);           // 36.77 MB
    // scratch union: [xTb | A | A2b | cnt | invdeg] overlaid later by partials
    char* uni = (char*)alloc((size_t)SPLITS * NN * H2 * 4);        // 37.75 MB
    __bf16* xTb = (__bf16*)uni;                                    // 17952*512*2 = 18.38 MB
    float* Adj = (float*)(uni + (size_t)17952 * NN * 2);           // 1 MB
    __bf16* A2b = (__bf16*)((char*)Adj + (size_t)NN * NN * 4);     // 0.5 MB
    int* cnt = (int*)((char*)A2b + (size_t)NN * NN * 2);           // 2 KB
    float* invdeg = (float*)((char*)cnt + 2048);                   // 2 KB
    float* partials = (float*)uni;                                 // overlays (safe after h2-GEMM)
    float* h = (float*)alloc((size_t)NN * H2 * 4);
    __bf16* hd_b = (__bf16*)alloc((size_t)NN * H2 * 2);

    // --- adjacency prep ---
    k_zero_int<<<2, 256, 0, stream>>>(cnt, NN);
    k_zero_f4<<<256, 256, 0, stream>>>((float4*)Adj, NN * NN / 4);
    k_deg<<<NE / 256, 256, 0, stream>>>(edst, cnt);
    k_invdeg<<<2, 256, 0, stream>>>(cnt, invdeg);
    k_scatter<<<NE / 256, 256, 0, stream>>>(esrc, edst, invdeg, Adj);
    k_a2<<<NN, 256, 0, stream>>>(Adj, A2b);

    // --- fused x transpose (bf16) + embb x-half (reads x once) ---
    dim3 gxt((NODELEN + 63) / 64, NN / 64);
    k_xt_emb<<<gxt, 256, 0, stream>>>(x, xTb, embb);
    k_pad<<<(NN * (KP1 - IN_DIM) + 255) / 256, 256, 0, stream>>>(embb);

    // --- h2 = A2 @ x  -> embb h2-half (bf16, col0 zero) ---
    dim3 gh2(NN / BM, (NODELEN + BN - 1) / BN, 1);
    gemm_k<2, true><<<gh2, 256, 0, stream>>>(
        A2b, NN, xTb, NN, NODELEN, NN, NN / BK, NN / BK,
        (float*)nullptr, 0, (const float*)nullptr, embb);

    // --- GEMM1: emb @ W_e2^T, split-K, W_e2 read as f32 directly ---
    dim3 g1(NN / BM, H2 / BN, SPLITS);
    gemm_k<0, false><<<g1, 256, 0, stream>>>(
        embb, KP1, W_e2, IN_DIM, H2, IN_DIM, KITERS1, KCHUNK1,
        partials, 0, (const float*)nullptr, (__bf16*)nullptr);

    k_reduce<<<(NN * H2) / 256, 256, 0, stream>>>(partials, b_e2, h);

    // --- encoded ---
    k_enc<<<NN, EMB, 0, stream>>>(h, W_e3, b_e3, out);

    // --- decoder hidden (bf16) ---
    k_dec1<<<NN, 256, 0, stream>>>(out, W_d1, b_d1, hd_b);

    // --- GEMM4: decoded = h_d @ W_d3^T + b_d3 ---
    dim3 g4(NN / BM, (IN_DIM + BN - 1) / BN, 1);
    gemm_k<1, false><<<g4, 256, 0, stream>>>(
        hd_b, H2, W_d3, H2, IN_DIM, H2, H2 / BK, H2 / BK,
        out + (size_t)NN * EMB, IN_DIM, b_d3, (__bf16*)nullptr);
}

// Round 2
// 647.682 us; speedup vs baseline: 1.2078x; 1.2078x over previous
//
#include <hip/hip_runtime.h>
#include <hip/hip_bf16.h>

#define NODELEN 17949
#define NN 512
#define NE 4096
#define H2 768
#define EMB 128
#define IN_DIM (2 * NODELEN)      // 35898
#define KP1 35904                 // IN_DIM padded to 64 (561 * 64)
#define KITERS1 561
#define SPLITS 24
#define KCHUNK1 24                // ceil(561/24)

#define BM 128
#define BN 128
#define BK 64
#define LDT (BK + 8)              // LDS row stride in bf16 (pad 16B; row stride 144B = 4-bank shift -> 2-way max, free)

typedef __bf16 bf16x8 __attribute__((ext_vector_type(8)));
typedef float f32x4 __attribute__((ext_vector_type(4)));

// ---------------- graph prep (dense adjacency) ----------------

__global__ void k_zero_int(int* p, int n) {
    int i = blockIdx.x * 256 + threadIdx.x;
    if (i < n) p[i] = 0;
}

__global__ void k_zero_f4(float4* p, int n4) {
    int i = blockIdx.x * 256 + threadIdx.x;
    if (i < n4) p[i] = make_float4(0.f, 0.f, 0.f, 0.f);
}

__global__ void k_deg(const int* __restrict__ dst, int* __restrict__ cnt) {
    int e = blockIdx.x * 256 + threadIdx.x;
    if (e < NE) atomicAdd(&cnt[dst[e]], 1);
}

__global__ void k_invdeg(const int* __restrict__ cnt, float* __restrict__ invdeg) {
    int i = blockIdx.x * 256 + threadIdx.x;
    if (i < NN) {
        int c = cnt[i];
        invdeg[i] = 1.0f / (float)(c > 1 ? c : 1);
    }
}

// A[dst][src] += 1/deg[dst]  (duplicates accumulate identical values -> order-safe)
__global__ void k_scatter(const int* __restrict__ src, const int* __restrict__ dst,
                          const float* __restrict__ invdeg, float* __restrict__ A) {
    int e = blockIdx.x * 256 + threadIdx.x;
    if (e < NE) {
        int d = dst[e];
        atomicAdd(&A[(size_t)d * NN + src[e]], invdeg[d]);
    }
}

// A2b = bf16(A @ A), exploiting row sparsity (uniform branch on broadcast value)
__global__ void k_a2(const float* __restrict__ A, __bf16* __restrict__ A2b) {
    int i = blockIdx.x;
    int t = threadIdx.x;   // 256
    __shared__ float row[NN];
    row[t] = A[(size_t)i * NN + t];
    row[t + 256] = A[(size_t)i * NN + 256 + t];
    __syncthreads();
    float a0 = 0.f, a1 = 0.f;
    for (int s = 0; s < NN; ++s) {
        float a = row[s];
        if (a != 0.f) {
            a0 += a * A[(size_t)s * NN + t];
            a1 += a * A[(size_t)s * NN + 256 + t];
        }
    }
    A2b[(size_t)i * NN + t] = (__bf16)a0;
    A2b[(size_t)i * NN + 256 + t] = (__bf16)a1;
}

// Fused: xT[f][s] = bf16(x[s][f]) (tiled transpose)  AND  embb x-half (col0 zero).
// Reads x exactly once.
__global__ void k_xt_emb(const float* __restrict__ x, __bf16* __restrict__ xT,
                         __bf16* __restrict__ embb) {
    __shared__ float t[64][65];
    int f0 = blockIdx.x * 64, s0 = blockIdx.y * 64;
    int tx = threadIdx.x & 63, ty = threadIdx.x >> 6;   // ty 0..3
#pragma unroll
    for (int r = 0; r < 16; ++r) {
        int f = f0 + tx;
        int s = s0 + ty * 16 + r;
        float v = (f < NODELEN) ? x[(size_t)s * NODELEN + f] : 0.f;
        t[ty * 16 + r][tx] = v;
        if (f < NODELEN)
            embb[(size_t)s * KP1 + f] = (__bf16)((f == 0) ? 0.f : v);
    }
    __syncthreads();
#pragma unroll
    for (int r = 0; r < 16; ++r) {
        int f = f0 + ty * 16 + r;
        if (f < NODELEN) xT[(size_t)f * NN + s0 + tx] = (__bf16)t[tx][ty * 16 + r];
    }
}

// zero pad cols [IN_DIM, KP1) of embb
__global__ void k_pad(__bf16* __restrict__ embb) {
    int i = blockIdx.x * 256 + threadIdx.x;
    const int PAD = KP1 - IN_DIM;   // 6
    if (i < NN * PAD) {
        int n = i / PAD, c = i % PAD;
        embb[(size_t)n * KP1 + IN_DIM + c] = (__bf16)0.f;
    }
}

// ---------------- MFMA GEMM: C[m][n] = sum_k A_bf16[m][k] * B[n][k] ----------------
// EPI: 0 = split-K partials (f32), 1 = f32 out + bias (n<Nvalid), 2 = bf16 out into
//      embb h2-half (col n==0 zeroed). BF16B: B is bf16 (plain copy staging) else f32
//      (converted during staging; Kvalid guards the k-tail).
// XCD-swizzled (logical x fastest -> same-B-panel blocks share an XCD L2).
// 2-phase LDS double-buffer (T3-minimum): STAGE(next tile -> other buffer) runs
// before COMPUTE(current buffer); one barrier per K-step. Staging registers live
// only inside STAGE (no cross-MFMA lifetimes -> no scratch spills).

template <int EPI, bool BF16B>
__global__ __launch_bounds__(256) void gemm_k(
        const __bf16* __restrict__ A, int lda,
        const void* __restrict__ Bv, int ldb,
        int Nvalid, int Kvalid, int kIters, int kChunk,
        float* __restrict__ Cf, int ldc, const float* __restrict__ bias,
        __bf16* __restrict__ Cb) {
    __shared__ __align__(16) __bf16 As[2][BM][LDT];
    __shared__ __align__(16) __bf16 Bs[2][BN][LDT];

    const int tid = threadIdx.x;

    // ---- XCD-aware bijective swizzle (dispatch fid -> XCD = fid % 8) ----
    const int gx = gridDim.x, gy = gridDim.y;
    const int nwg = gx * gy * (int)gridDim.z;
    const int fid = blockIdx.x + gx * (blockIdx.y + gy * blockIdx.z);
    const int q = nwg >> 3, r = nwg & 7;
    const int xcd = fid & 7, idx = fid >> 3;
    const int lid = (xcd < r) ? xcd * (q + 1) + idx
                              : r * (q + 1) + (xcd - r) * q + idx;
    const int m0 = (lid % gx) * BM;
    const int rem = lid / gx;
    const int n0 = (rem % gy) * BN;
    const int z = rem / gy;

    int it0 = z * kChunk;
    int it1 = it0 + kChunk;
    if (it1 > kIters) it1 = kIters;

    const int wave = tid >> 6;
    const int lane = tid & 63;
    const int wm = (wave & 1) * 64;
    const int wn = (wave >> 1) * 64;
    const int fl = lane & 15;
    const int fq = lane >> 4;

    const int srow = tid >> 1;       // 0..127
    const int spart = tid & 1;       // k offset 0/32

    f32x4 acc[4][4] = {};

    const int bn = n0 + srow;
    const bool nok = bn < Nvalid;
    const __bf16* Arow = A + (size_t)(m0 + srow) * lda + spart * 32;
    const __bf16* Brow_h = (const __bf16*)Bv + (size_t)bn * ldb + spart * 32;
    const float* Brow_f = (const float*)Bv + (size_t)bn * ldb + spart * 32;

    // stage tile `it` into buffer b (0/1, literal at call sites).
    // loads issued together first, then LDS writes; all regs die inside.
    auto STAGE = [&](int it, int b) {
        const int k0 = it * BK;
        uint4 av[4];
        const uint4* Ag = (const uint4*)(Arow + k0);
#pragma unroll
        for (int i = 0; i < 4; ++i) av[i] = Ag[i];

        if (BF16B) {
            uint4 bv[4];
            if (nok) {
                const uint4* Bg = (const uint4*)(Brow_h + k0);
#pragma unroll
                for (int i = 0; i < 4; ++i) bv[i] = Bg[i];
            } else {
#pragma unroll
                for (int i = 0; i < 4; ++i) bv[i] = make_uint4(0, 0, 0, 0);
            }
#pragma unroll
            for (int i = 0; i < 4; ++i)
                *(uint4*)&As[b][srow][spart * 32 + i * 8] = av[i];
#pragma unroll
            for (int i = 0; i < 4; ++i)
                *(uint4*)&Bs[b][srow][spart * 32 + i * 8] = bv[i];
        } else {
            float4 bf4[8];
            if (nok && (k0 + spart * 32 + 32 <= Kvalid)) {
                const float4* Bg = (const float4*)(Brow_f + k0);
#pragma unroll
                for (int j = 0; j < 8; ++j) bf4[j] = Bg[j];
            } else {
#pragma unroll
                for (int j = 0; j < 8; ++j) {
                    int kb = k0 + spart * 32 + j * 4;
                    float4 v;
                    v.x = (nok && kb + 0 < Kvalid) ? Brow_f[k0 + j * 4 + 0] : 0.f;
                    v.y = (nok && kb + 1 < Kvalid) ? Brow_f[k0 + j * 4 + 1] : 0.f;
                    v.z = (nok && kb + 2 < Kvalid) ? Brow_f[k0 + j * 4 + 2] : 0.f;
                    v.w = (nok && kb + 3 < Kvalid) ? Brow_f[k0 + j * 4 + 3] : 0.f;
                    bf4[j] = v;
                }
            }
#pragma unroll
            for (int i = 0; i < 4; ++i)
                *(uint4*)&As[b][srow][spart * 32 + i * 8] = av[i];
            __align__(16) __bf16 bl[32];
#pragma unroll
            for (int j = 0; j < 8; ++j) {
                bl[4 * j + 0] = (__bf16)bf4[j].x;
                bl[4 * j + 1] = (__bf16)bf4[j].y;
                bl[4 * j + 2] = (__bf16)bf4[j].z;
                bl[4 * j + 3] = (__bf16)bf4[j].w;
            }
#pragma unroll
            for (int qq = 0; qq < 4; ++qq)
                *(uint4*)&Bs[b][srow][spart * 32 + qq * 8] = *(uint4*)&bl[qq * 8];
        }
    };

    auto COMPUTE = [&](int b) {
#pragma unroll
        for (int ks = 0; ks < 2; ++ks) {
            int kk = ks * 32 + fq * 8;
            bf16x8 af[4], bfr[4];
#pragma unroll
            for (int i = 0; i < 4; ++i)
                af[i] = *(const bf16x8*)&As[b][wm + i * 16 + fl][kk];
#pragma unroll
            for (int j = 0; j < 4; ++j)
                bfr[j] = *(const bf16x8*)&Bs[b][wn + j * 16 + fl][kk];
#pragma unroll
            for (int i = 0; i < 4; ++i)
#pragma unroll
                for (int j = 0; j < 4; ++j)
                    acc[i][j] = __builtin_amdgcn_mfma_f32_16x16x32_bf16(
                        af[i], bfr[j], acc[i][j], 0, 0, 0);
        }
    };

    // ---- pipelined K loop: 1 barrier per K-step ----
    if (it0 < it1) STAGE(it0, 0);
    __syncthreads();
    int it = it0;
    while (it + 2 <= it1) {
        STAGE(it + 1, 1);          // loads fly under COMPUTE(0)
        COMPUTE(0);
        __syncthreads();
        if (it + 2 < it1) STAGE(it + 2, 0);
        COMPUTE(1);
        __syncthreads();
        it += 2;
    }
    if (it < it1) COMPUTE(0);      // odd tail (staged by last loop iteration / prologue)

    // epilogue
#pragma unroll
    for (int i = 0; i < 4; ++i) {
#pragma unroll
        for (int j = 0; j < 4; ++j) {
#pragma unroll
            for (int rr = 0; rr < 4; ++rr) {
                int m = m0 + wm + i * 16 + fq * 4 + rr;
                int n = n0 + wn + j * 16 + fl;
                float v = acc[i][j][rr];
                if (EPI == 0) {
                    Cf[((size_t)z * NN + m) * H2 + n] = v;
                } else if (EPI == 1) {
                    if (n < Nvalid) Cf[(size_t)m * ldc + n] = v + bias[n];
                } else {
                    if (n < Nvalid)
                        Cb[(size_t)m * KP1 + NODELEN + n] = (n == 0) ? (__bf16)0.f : (__bf16)v;
                }
            }
        }
    }
}

// h = relu(sum_z partials + b_e2)
__global__ void k_reduce(const float* __restrict__ partials,
                         const float* __restrict__ bias, float* __restrict__ h) {
    int idx = blockIdx.x * 256 + threadIdx.x;
    if (idx >= NN * H2) return;
    float s = 0.f;
#pragma unroll
    for (int zz = 0; zz < SPLITS; ++zz) s += partials[(size_t)zz * NN * H2 + idx];
    s += bias[idx % H2];
    h[idx] = s > 0.f ? s : 0.f;
}

// encoded[m][e] = h[m] . W_e3[e] + b_e3[e]
__global__ void k_enc(const float* __restrict__ h, const float* __restrict__ W,
                      const float* __restrict__ b, float* __restrict__ out) {
    int m = blockIdx.x, e = threadIdx.x;
    const float4* hr = (const float4*)(h + (size_t)m * H2);
    const float4* wr = (const float4*)(W + (size_t)e * H2);
    float s = 0.f;
#pragma unroll 4
    for (int i = 0; i < H2 / 4; ++i) {
        float4 a = hr[i];
        float4 w = wr[i];
        s += a.x * w.x + a.y * w.y + a.z * w.z + a.w * w.w;
    }
    out[(size_t)m * EMB + e] = s + b[e];
}

// hd_b[m][j] = bf16(relu(enc[m] . W_d1[j] + b_d1[j]))
__global__ void k_dec1(const float* __restrict__ enc, const float* __restrict__ W,
                       const float* __restrict__ b, __bf16* __restrict__ hd) {
    int m = blockIdx.x;
    __shared__ float er[EMB];
    if (threadIdx.x < EMB) er[threadIdx.x] = enc[(size_t)m * EMB + threadIdx.x];
    __syncthreads();
    for (int j = threadIdx.x; j < H2; j += 256) {
        const float4* wr = (const float4*)(W + (size_t)j * EMB);
        float s = 0.f;
#pragma unroll
        for (int i = 0; i < EMB / 4; ++i) {
            float4 w = wr[i];
            s += w.x * er[4 * i] + w.y * er[4 * i + 1] + w.z * er[4 * i + 2] +
                 w.w * er[4 * i + 3];
        }
        float v = s + b[j];
        hd[(size_t)m * H2 + j] = (__bf16)(v > 0.f ? v : 0.f);
    }
}

// ---------------- launch ----------------

extern "C" void kernel_launch(void* const* d_in, const int* in_sizes, int n_in,
                              void* d_out, int out_size, void* d_ws, size_t ws_size,
                              hipStream_t stream) {
    const float* x = (const float*)d_in[0];
    const int* esrc = (const int*)d_in[1];
    const int* edst = (const int*)d_in[2];
    const float* W_e2 = (const float*)d_in[3];
    const float* b_e2 = (const float*)d_in[4];
    const float* W_e3 = (const float*)d_in[5];
    const float* b_e3 = (const float*)d_in[6];
    const float* W_d1 = (const float*)d_in[7];
    const float* b_d1 = (const float*)d_in[8];
    const float* W_d3 = (const float*)d_in[9];
    const float* b_d3 = (const float*)d_in[10];
    float* out = (float*)d_out;

    char* w = (char*)d_ws;
    auto alloc = [&](size_t bytes) {
        char* p = w;
        w += (bytes + 255) & ~(size_t)255;
        return p;
    };
    __bf16* embb = (__bf16*)alloc((size_t)NN * KP1 * 2);           // 36.77 MB
    // scratch union: [xTb | A | A2b | cnt | invdeg] overlaid later by partials
    char* uni = (char*)alloc((size_t)SPLITS * NN * H2 * 4);        // 37.75 MB
    __bf16* xTb = (__bf16*)uni;                                    // 17952*512*2 = 18.38 MB
    float* Adj = (float*)(uni + (size_t)17952 * NN * 2);           // 1 MB
    __bf16* A2b = (__bf16*)((char*)Adj + (size_t)NN * NN * 4);     // 0.5 MB
    int* cnt = (int*)((char*)A2b + (size_t)NN * NN * 2);           // 2 KB
    float* invdeg = (float*)((char*)cnt + 2048);                   // 2 KB
    float* partials = (float*)uni;                                 // overlays (safe after h2-GEMM)
    float* h = (float*)alloc((size_t)NN * H2 * 4);
    __bf16* hd_b = (__bf16*)alloc((size_t)NN * H2 * 2);

    // --- adjacency prep ---
    k_zero_int<<<2, 256, 0, stream>>>(cnt, NN);
    k_zero_f4<<<256, 256, 0, stream>>>((float4*)Adj, NN * NN / 4);
    k_deg<<<NE / 256, 256, 0, stream>>>(edst, cnt);
    k_invdeg<<<2, 256, 0, stream>>>(cnt, invdeg);
    k_scatter<<<NE / 256, 256, 0, stream>>>(esrc, edst, invdeg, Adj);
    k_a2<<<NN, 256, 0, stream>>>(Adj, A2b);

    // --- fused x transpose (bf16) + embb x-half (reads x once) ---
    dim3 gxt((NODELEN + 63) / 64, NN / 64);
    k_xt_emb<<<gxt, 256, 0, stream>>>(x, xTb, embb);
    k_pad<<<(NN * (KP1 - IN_DIM) + 255) / 256, 256, 0, stream>>>(embb);

    // --- h2 = A2 @ x  -> embb h2-half (bf16, col0 zero) ---
    dim3 gh2(NN / BM, (NODELEN + BN - 1) / BN, 1);
    gemm_k<2, true><<<gh2, 256, 0, stream>>>(
        A2b, NN, xTb, NN, NODELEN, NN, NN / BK, NN / BK,
        (float*)nullptr, 0, (const float*)nullptr, embb);

    // --- GEMM1: emb @ W_e2^T, split-K, W_e2 read as f32 directly ---
    dim3 g1(NN / BM, H2 / BN, SPLITS);
    gemm_k<0, false><<<g1, 256, 0, stream>>>(
        embb, KP1, W_e2, IN_DIM, H2, IN_DIM, KITERS1, KCHUNK1,
        partials, 0, (const float*)nullptr, (__bf16*)nullptr);

    k_reduce<<<(NN * H2) / 256, 256, 0, stream>>>(partials, b_e2, h);

    // --- encoded ---
    k_enc<<<NN, EMB, 0, stream>>>(h, W_e3, b_e3, out);

    // --- decoder hidden (bf16) ---
    k_dec1<<<NN, 256, 0, stream>>>(out, W_d1, b_d1, hd_b);

    // --- GEMM4: decoded = h_d @ W_d3^T + b_d3 ---
    dim3 g4(NN / BM, (IN_DIM + BN - 1) / BN, 1);
    gemm_k<1, false><<<g4, 256, 0, stream>>>(
        hd_b, H2, W_d3, H2, IN_DIM, H2, H2 / BK, H2 / BK,
        out + (size_t)NN * EMB, IN_DIM, b_d3, (__bf16*)nullptr);
}

// Round 3
// 545.351 us; speedup vs baseline: 1.4345x; 1.1876x over previous
//
#include <hip/hip_runtime.h>
#include <hip/hip_bf16.h>

#define NODELEN 17949
#define NN 512
#define NE 4096
#define H2 768
#define EMB 128
#define IN_DIM (2 * NODELEN)      // 35898
#define KP1 35904                 // IN_DIM padded to 64 (561 * 64)
#define KITERS1 561
#define SPLITS 24
#define KCHUNK1 24                // ceil(561/24)
#define FPAD 18048                // NODELEN padded to 128 (141 * 128)
#define RPAD4 35968               // IN_DIM padded to 128 (281 * 128)

#define BM 128
#define BN 128
#define BK 64

typedef __bf16 bf16x8 __attribute__((ext_vector_type(8)));
typedef float f32x4 __attribute__((ext_vector_type(4)));

#define GPTR(p) ((const __attribute__((address_space(1))) void*)(p))
#define LPTR(p) ((__attribute__((address_space(3))) void*)(p))

// ---------------- graph prep (dense adjacency) ----------------

__global__ void k_zero_int(int* p, int n) {
    int i = blockIdx.x * 256 + threadIdx.x;
    if (i < n) p[i] = 0;
}

__global__ void k_zero_f4(float4* p, int n4) {
    int i = blockIdx.x * 256 + threadIdx.x;
    if (i < n4) p[i] = make_float4(0.f, 0.f, 0.f, 0.f);
}

__global__ void k_deg(const int* __restrict__ dst, int* __restrict__ cnt) {
    int e = blockIdx.x * 256 + threadIdx.x;
    if (e < NE) atomicAdd(&cnt[dst[e]], 1);
}

__global__ void k_invdeg(const int* __restrict__ cnt, float* __restrict__ invdeg) {
    int i = blockIdx.x * 256 + threadIdx.x;
    if (i < NN) {
        int c = cnt[i];
        invdeg[i] = 1.0f / (float)(c > 1 ? c : 1);
    }
}

// A[dst][src] += 1/deg[dst]  (duplicates accumulate identical values -> order-safe)
__global__ void k_scatter(const int* __restrict__ src, const int* __restrict__ dst,
                          const float* __restrict__ invdeg, float* __restrict__ A) {
    int e = blockIdx.x * 256 + threadIdx.x;
    if (e < NE) {
        int d = dst[e];
        atomicAdd(&A[(size_t)d * NN + src[e]], invdeg[d]);
    }
}

// A2b = bf16(A @ A), exploiting row sparsity (uniform branch on broadcast value)
__global__ void k_a2(const float* __restrict__ A, __bf16* __restrict__ A2b) {
    int i = blockIdx.x;
    int t = threadIdx.x;   // 256
    __shared__ float row[NN];
    row[t] = A[(size_t)i * NN + t];
    row[t + 256] = A[(size_t)i * NN + 256 + t];
    __syncthreads();
    float a0 = 0.f, a1 = 0.f;
    for (int s = 0; s < NN; ++s) {
        float a = row[s];
        if (a != 0.f) {
            a0 += a * A[(size_t)s * NN + t];
            a1 += a * A[(size_t)s * NN + 256 + t];
        }
    }
    A2b[(size_t)i * NN + t] = (__bf16)a0;
    A2b[(size_t)i * NN + 256 + t] = (__bf16)a1;
}

// Fused: xT[f][s] = bf16(x[s][f]) for f < FPAD (zero rows beyond NODELEN)
// AND embb x-half (col0 zero). Reads x exactly once.
__global__ void k_xt_emb(const float* __restrict__ x, __bf16* __restrict__ xT,
                         __bf16* __restrict__ embb) {
    __shared__ float t[64][65];
    int f0 = blockIdx.x * 64, s0 = blockIdx.y * 64;
    int tx = threadIdx.x & 63, ty = threadIdx.x >> 6;   // ty 0..3
#pragma unroll
    for (int r = 0; r < 16; ++r) {
        int f = f0 + tx;
        int s = s0 + ty * 16 + r;
        float v = (f < NODELEN) ? x[(size_t)s * NODELEN + f] : 0.f;
        t[ty * 16 + r][tx] = v;
        if (f < NODELEN)
            embb[(size_t)s * KP1 + f] = (__bf16)((f == 0) ? 0.f : v);
    }
    __syncthreads();
#pragma unroll
    for (int r = 0; r < 16; ++r) {
        int f = f0 + ty * 16 + r;
        if (f < FPAD) xT[(size_t)f * NN + s0 + tx] = (__bf16)t[tx][ty * 16 + r];
    }
}

// zero pad cols [IN_DIM, KP1) of embb
__global__ void k_pad(__bf16* __restrict__ embb) {
    int i = blockIdx.x * 256 + threadIdx.x;
    const int PAD = KP1 - IN_DIM;   // 6
    if (i < NN * PAD) {
        int n = i / PAD, c = i % PAD;
        embb[(size_t)n * KP1 + IN_DIM + c] = (__bf16)0.f;
    }
}

// generic f32[R][C] -> bf16[Rpad][Cpad] converter, zero-fills pad region
__global__ void k_cvt(const float* __restrict__ src, __bf16* __restrict__ dst,
                      int R, int C, int Rpad, int Cpad) {
    int C8 = Cpad / 8;
    int idx = blockIdx.x * 256 + threadIdx.x;
    if (idx >= Rpad * C8) return;
    int r = idx / C8, c8 = (idx % C8) * 8;
    __align__(16) __bf16 o[8];
    if (r < R && c8 + 8 <= C) {
        const float2* p = (const float2*)(src + (size_t)r * C + c8);
#pragma unroll
        for (int j = 0; j < 4; ++j) {
            float2 f = p[j];
            o[2 * j] = (__bf16)f.x;
            o[2 * j + 1] = (__bf16)f.y;
        }
    } else {
#pragma unroll
        for (int j = 0; j < 8; ++j) {
            int c = c8 + j;
            o[j] = (r < R && c < C) ? (__bf16)src[(size_t)r * C + c] : (__bf16)0.f;
        }
    }
    *(uint4*)&dst[(size_t)r * Cpad + c8] = *(uint4*)o;
}

// ---------------- MFMA GEMM: C[m][n] = sum_k A[m][k] * B[n][k], all bf16 ----------------
// m97-proven structure: single-buffer LINEAR LDS (32 KB), global_load_lds dwordx4
// staging (no VGPR round-trip, no addr-calc VALU), 2 barriers per K-step, TLP from
// 4 blocks/CU does the latency hiding. XCD-swizzled (logical x fastest -> the m-blocks
// sharing a B panel live on one XCD's L2). B buffers are row-padded to BN multiples
// so staging needs no guards; Nvalid guards the epilogue only.
// EPI: 0 = split-K partials (f32), 1 = f32 out + bias, 2 = bf16 out into embb h2-half.

template <int EPI>
__global__ __launch_bounds__(256, 4) void gemm_k(
        const __bf16* __restrict__ A, int lda,
        const __bf16* __restrict__ B, int ldb,
        int Nvalid, int kIters, int kChunk,
        float* __restrict__ Cf, int ldc, const float* __restrict__ bias,
        __bf16* __restrict__ Cb) {
    __shared__ __align__(16) __bf16 As[BM * BK];   // linear [row][64], 16 KB
    __shared__ __align__(16) __bf16 Bs[BN * BK];   // linear [row][64], 16 KB

    const int tid = threadIdx.x;

    // ---- XCD-aware bijective swizzle (dispatch fid -> XCD = fid % 8) ----
    const int gx = gridDim.x, gy = gridDim.y;
    const int nwg = gx * gy * (int)gridDim.z;
    const int fid = blockIdx.x + gx * (blockIdx.y + gy * blockIdx.z);
    const int q = nwg >> 3, r = nwg & 7;
    const int xcd = fid & 7, idx = fid >> 3;
    const int lid = (xcd < r) ? xcd * (q + 1) + idx
                              : r * (q + 1) + (xcd - r) * q + idx;
    const int m0 = (lid % gx) * BM;
    const int rem = lid / gx;
    const int n0 = (rem % gy) * BN;
    const int z = rem / gy;

    int it0 = z * kChunk;
    int it1 = it0 + kChunk;
    if (it1 > kIters) it1 = kIters;

    const int wave = tid >> 6;
    const int lane = tid & 63;
    const int wm = (wave & 1) * 64;
    const int wn = (wave >> 1) * 64;
    const int fl = lane & 15;
    const int fq = lane >> 4;

    // staging geometry: round rr (0..3), thread t -> row rr*32 + t/8, col (t&7)*8.
    // LDS byte offset = rr*4096 + t*16 = rr*4096 + wave*1024 + lane*16
    //  -> wave-uniform LDS base + lane*16, exactly global_load_lds's write pattern.
    const __bf16* Abase = A + (size_t)(m0 + (tid >> 3)) * lda + (tid & 7) * 8;
    const __bf16* Bbase = B + (size_t)(n0 + (tid >> 3)) * ldb + (tid & 7) * 8;
    char* AsW = (char*)As + wave * 1024;
    char* BsW = (char*)Bs + wave * 1024;

    f32x4 acc[4][4] = {};

    for (int it = it0; it < it1; ++it) {
        const __bf16* Ag = Abase + it * BK;
        const __bf16* Bg = Bbase + it * BK;
#pragma unroll
        for (int rr = 0; rr < 4; ++rr)
            __builtin_amdgcn_global_load_lds(
                GPTR(Ag + (size_t)rr * 32 * lda), LPTR(AsW + rr * 4096), 16, 0, 0);
#pragma unroll
        for (int rr = 0; rr < 4; ++rr)
            __builtin_amdgcn_global_load_lds(
                GPTR(Bg + (size_t)rr * 32 * ldb), LPTR(BsW + rr * 4096), 16, 0, 0);
        __syncthreads();   // compiler drains vmcnt before s_barrier

#pragma unroll
        for (int ks = 0; ks < 2; ++ks) {
            const int kk = ks * 32 + fq * 8;
            bf16x8 af[4], bfr[4];
#pragma unroll
            for (int i = 0; i < 4; ++i)
                af[i] = *(const bf16x8*)&As[(wm + i * 16 + fl) * BK + kk];
#pragma unroll
            for (int j = 0; j < 4; ++j)
                bfr[j] = *(const bf16x8*)&Bs[(wn + j * 16 + fl) * BK + kk];
#pragma unroll
            for (int i = 0; i < 4; ++i)
#pragma unroll
                for (int j = 0; j < 4; ++j)
                    acc[i][j] = __builtin_amdgcn_mfma_f32_16x16x32_bf16(
                        af[i], bfr[j], acc[i][j], 0, 0, 0);
        }
        __syncthreads();
    }

    // epilogue
#pragma unroll
    for (int i = 0; i < 4; ++i) {
#pragma unroll
        for (int j = 0; j < 4; ++j) {
#pragma unroll
            for (int rr = 0; rr < 4; ++rr) {
                int m = m0 + wm + i * 16 + fq * 4 + rr;
                int n = n0 + wn + j * 16 + fl;
                float v = acc[i][j][rr];
                if (EPI == 0) {
                    Cf[((size_t)z * NN + m) * H2 + n] = v;
                } else if (EPI == 1) {
                    if (n < Nvalid) Cf[(size_t)m * ldc + n] = v + bias[n];
                } else {
                    if (n < Nvalid)
                        Cb[(size_t)m * KP1 + NODELEN + n] = (n == 0) ? (__bf16)0.f : (__bf16)v;
                }
            }
        }
    }
}

// h = relu(sum_z partials + b_e2), float4-vectorized
__global__ void k_reduce(const float* __restrict__ partials,
                         const float* __restrict__ bias, float* __restrict__ h) {
    const int T4 = NN * H2 / 4;
    int i4 = blockIdx.x * 256 + threadIdx.x;
    if (i4 >= T4) return;
    const float4* p = (const float4*)partials;
    float4 s = make_float4(0.f, 0.f, 0.f, 0.f);
#pragma unroll
    for (int zz = 0; zz < SPLITS; ++zz) {
        float4 v = p[(size_t)zz * T4 + i4];
        s.x += v.x; s.y += v.y; s.z += v.z; s.w += v.w;
    }
    const float4 b = *(const float4*)&bias[(i4 * 4) % H2];
    s.x += b.x; s.y += b.y; s.z += b.z; s.w += b.w;
    s.x = s.x > 0.f ? s.x : 0.f;
    s.y = s.y > 0.f ? s.y : 0.f;
    s.z = s.z > 0.f ? s.z : 0.f;
    s.w = s.w > 0.f ? s.w : 0.f;
    *(float4*)&h[(size_t)i4 * 4] = s;
}

// encoded[m][e] = h[m] . W_e3[e] + b_e3[e]
__global__ void k_enc(const float* __restrict__ h, const float* __restrict__ W,
                      const float* __restrict__ b, float* __restrict__ out) {
    int m = blockIdx.x, e = threadIdx.x;
    const float4* hr = (const float4*)(h + (size_t)m * H2);
    const float4* wr = (const float4*)(W + (size_t)e * H2);
    float s = 0.f;
#pragma unroll 4
    for (int i = 0; i < H2 / 4; ++i) {
        float4 a = hr[i];
        float4 w = wr[i];
        s += a.x * w.x + a.y * w.y + a.z * w.z + a.w * w.w;
    }
    out[(size_t)m * EMB + e] = s + b[e];
}

// hd_b[m][j] = bf16(relu(enc[m] . W_d1[j] + b_d1[j]))
__global__ void k_dec1(const float* __restrict__ enc, const float* __restrict__ W,
                       const float* __restrict__ b, __bf16* __restrict__ hd) {
    int m = blockIdx.x;
    __shared__ float er[EMB];
    if (threadIdx.x < EMB) er[threadIdx.x] = enc[(size_t)m * EMB + threadIdx.x];
    __syncthreads();
    for (int j = threadIdx.x; j < H2; j += 256) {
        const float4* wr = (const float4*)(W + (size_t)j * EMB);
        float s = 0.f;
#pragma unroll
        for (int i = 0; i < EMB / 4; ++i) {
            float4 w = wr[i];
            s += w.x * er[4 * i] + w.y * er[4 * i + 1] + w.z * er[4 * i + 2] +
                 w.w * er[4 * i + 3];
        }
        float v = s + b[j];
        hd[(size_t)m * H2 + j] = (__bf16)(v > 0.f ? v : 0.f);
    }
}

// ---------------- launch ----------------

extern "C" void kernel_launch(void* const* d_in, const int* in_sizes, int n_in,
                              void* d_out, int out_size, void* d_ws, size_t ws_size,
                              hipStream_t stream) {
    const float* x = (const float*)d_in[0];
    const int* esrc = (const int*)d_in[1];
    const int* edst = (const int*)d_in[2];
    const float* W_e2 = (const float*)d_in[3];
    const float* b_e2 = (const float*)d_in[4];
    const float* W_e3 = (const float*)d_in[5];
    const float* b_e3 = (const float*)d_in[6];
    const float* W_d1 = (const float*)d_in[7];
    const float* b_d1 = (const float*)d_in[8];
    const float* W_d3 = (const float*)d_in[9];
    const float* b_d3 = (const float*)d_in[10];
    float* out = (float*)d_out;

    char* w = (char*)d_ws;
    auto alloc = [&](size_t bytes) {
        char* p = w;
        w += (bytes + 255) & ~(size_t)255;
        return p;
    };
    __bf16* embb = (__bf16*)alloc((size_t)NN * KP1 * 2);           // 36.77 MB
    // scratch union: [xTb | A | A2b | cnt | invdeg] overlaid later by partials
    char* uni = (char*)alloc((size_t)SPLITS * NN * H2 * 4);        // 37.75 MB
    __bf16* xTb = (__bf16*)uni;                                    // FPAD*512*2 = 18.48 MB
    float* Adj = (float*)(uni + (size_t)FPAD * NN * 2);            // 1 MB
    __bf16* A2b = (__bf16*)((char*)Adj + (size_t)NN * NN * 4);     // 0.5 MB
    int* cnt = (int*)((char*)A2b + (size_t)NN * NN * 2);           // 2 KB
    float* invdeg = (float*)((char*)cnt + 2048);                   // 2 KB
    float* partials = (float*)uni;                                 // overlays (safe after h2-GEMM)
    // Wbig: holds We2b for GEMM1, then Wd3b overlays it after GEMM1 completes
    char* Wbig = alloc((size_t)RPAD4 * H2 * 2);                    // 55.25 MB (>= 768*KP1*2)
    __bf16* We2b = (__bf16*)Wbig;
    __bf16* Wd3b = (__bf16*)Wbig;
    float* h = (float*)alloc((size_t)NN * H2 * 4);
    __bf16* hd_b = (__bf16*)alloc((size_t)NN * H2 * 2);

    // --- adjacency prep ---
    k_zero_int<<<2, 256, 0, stream>>>(cnt, NN);
    k_zero_f4<<<256, 256, 0, stream>>>((float4*)Adj, NN * NN / 4);
    k_deg<<<NE / 256, 256, 0, stream>>>(edst, cnt);
    k_invdeg<<<2, 256, 0, stream>>>(cnt, invdeg);
    k_scatter<<<NE / 256, 256, 0, stream>>>(esrc, edst, invdeg, Adj);
    k_a2<<<NN, 256, 0, stream>>>(Adj, A2b);

    // --- fused x transpose (bf16, rows padded to FPAD) + embb x-half ---
    dim3 gxt(FPAD / 64, NN / 64);
    k_xt_emb<<<gxt, 256, 0, stream>>>(x, xTb, embb);
    k_pad<<<(NN * (KP1 - IN_DIM) + 255) / 256, 256, 0, stream>>>(embb);

    // --- h2 = A2 @ x  -> embb h2-half (bf16, col0 zero) ---
    dim3 gh2(NN / BM, FPAD / BN, 1);
    gemm_k<2><<<gh2, 256, 0, stream>>>(
        A2b, NN, xTb, NN, NODELEN, NN / BK, NN / BK,
        (float*)nullptr, 0, (const float*)nullptr, embb);

    // --- W_e2 -> bf16 [768][KP1] ---
    k_cvt<<<(H2 * (KP1 / 8) + 255) / 256, 256, 0, stream>>>(
        W_e2, We2b, H2, IN_DIM, H2, KP1);

    // --- GEMM1: emb @ W_e2^T, split-K (overlays scratch with partials) ---
    dim3 g1(NN / BM, H2 / BN, SPLITS);
    gemm_k<0><<<g1, 256, 0, stream>>>(
        embb, KP1, We2b, KP1, H2, KITERS1, KCHUNK1,
        partials, 0, (const float*)nullptr, (__bf16*)nullptr);

    // --- W_d3 -> bf16 [RPAD4][768] (reuses We2b space; after GEMM1 in stream order) ---
    k_cvt<<<(RPAD4 * (H2 / 8) + 255) / 256, 256, 0, stream>>>(
        W_d3, Wd3b, IN_DIM, H2, RPAD4, H2);

    k_reduce<<<(NN * H2 / 4 + 255) / 256, 256, 0, stream>>>(partials, b_e2, h);

    // --- encoded ---
    k_enc<<<NN, EMB, 0, stream>>>(h, W_e3, b_e3, out);

    // --- decoder hidden (bf16) ---
    k_dec1<<<NN, 256, 0, stream>>>(out, W_d1, b_d1, hd_b);

    // --- GEMM4: decoded = h_d @ W_d3^T + b_d3 ---
    dim3 g4(NN / BM, RPAD4 / BN, 1);
    gemm_k<1><<<g4, 256, 0, stream>>>(
        hd_b, H2, Wd3b, H2, IN_DIM, H2 / BK, H2 / BK,
        out + (size_t)NN * EMB, IN_DIM, b_d3, (__bf16*)nullptr);
}